// Round 1
// baseline (231.907 us; speedup 1.0000x reference)
//
#include <hip/hip_runtime.h>
#include <cmath>

#define NB 2048
#define NL 375
#define NEMB 32
#define DIN 480   // 15 * 32

// ---------------------------------------------------------------------------
// Kernel 1: sequence features — gather [B,L,32] and mean-pool over L -> x0
// One block per (batch row, feature). float2 loads: 16 lanes cover one 128B
// row, so a wave64 load instruction fetches 4 table rows.
// ---------------------------------------------------------------------------
struct SeqArgs {
  const int*   idx[9];
  const float* tab[9];
};

__global__ __launch_bounds__(256) void seq_pool_kernel(SeqArgs args, float* __restrict__ x0) {
  const int b   = blockIdx.x;
  const int f   = blockIdx.y;
  const int tid = threadIdx.x;

  __shared__ int sidx[NL];
  const int*   idx = args.idx[f];
  const float* tab = args.tab[f];

  for (int i = tid; i < NL; i += 256) sidx[i] = idx[b * NL + i];
  __syncthreads();

  const int c = tid & 15;   // float2 column within the 32-float row
  const int s = tid >> 4;   // 0..15 slice over sequence positions

  float2 acc = make_float2(0.f, 0.f);
  for (int l = s; l < NL; l += 16) {
    const float2* row = reinterpret_cast<const float2*>(tab) + (size_t)sidx[l] * 16;
    float2 v = row[c];
    acc.x += v.x;
    acc.y += v.y;
  }

  __shared__ float2 red[16][16];
  red[s][c] = acc;
  __syncthreads();

  if (s == 0) {
    float2 sum = make_float2(0.f, 0.f);
    #pragma unroll
    for (int k = 0; k < 16; ++k) { sum.x += red[k][c].x; sum.y += red[k][c].y; }
    const float inv = 1.0f / (float)NL;
    float* out = x0 + (size_t)b * DIN + (6 + f) * NEMB + c * 2;
    out[0] = sum.x * inv;
    out[1] = sum.y * inv;
  }
}

// ---------------------------------------------------------------------------
// Kernel 2: scalar features — single-row gather -> x0
// ---------------------------------------------------------------------------
struct ScalArgs {
  const int*   idx[6];
  const float* tab[6];
};

__global__ __launch_bounds__(256) void scalar_gather_kernel(ScalArgs args, float* __restrict__ x0) {
  int e = blockIdx.x * 256 + threadIdx.x;   // total NB*6*32
  if (e >= NB * 6 * NEMB) return;
  int d = e & 31;
  int f = (e >> 5) % 6;
  int b = e / (6 * NEMB);
  int ix = args.idx[f][b];
  x0[(size_t)b * DIN + f * NEMB + d] = args.tab[f][(size_t)ix * NEMB + d];
}

// ---------------------------------------------------------------------------
// Kernel 3: DCN cross layer, in-place on x0. One wave per row.
// proj = (x0 @ V) @ U + b ;  x = x0 * proj + x0
// ---------------------------------------------------------------------------
__global__ __launch_bounds__(64) void cross_kernel(float* __restrict__ x0,
                                                   const float* __restrict__ V,
                                                   const float* __restrict__ U,
                                                   const float* __restrict__ bias) {
  const int b    = blockIdx.x;
  const int lane = threadIdx.x;
  float* row = x0 + (size_t)b * DIN;

  float xv[8];
  float t[5] = {0.f, 0.f, 0.f, 0.f, 0.f};
  #pragma unroll
  for (int i = 0; i < 8; ++i) {
    int j = lane + i * 64;
    if (j < DIN) {
      xv[i] = row[j];
      #pragma unroll
      for (int p = 0; p < 5; ++p) t[p] += xv[i] * V[j * 5 + p];
    } else {
      xv[i] = 0.f;
    }
  }
  #pragma unroll
  for (int p = 0; p < 5; ++p) {
    float v = t[p];
    for (int off = 32; off; off >>= 1) v += __shfl_xor(v, off, 64);
    t[p] = v;
  }
  #pragma unroll
  for (int i = 0; i < 8; ++i) {
    int j = lane + i * 64;
    if (j < DIN) {
      float proj = bias[j];
      #pragma unroll
      for (int p = 0; p < 5; ++p) proj += t[p] * U[p * DIN + j];
      row[j] = xv[i] * proj + xv[i];
    }
  }
}

// ---------------------------------------------------------------------------
// Kernel 4: fp32 tiled GEMM, C = relu?(A[M,K] @ W[K,N] + bias)
// 64x64 tile, BK=16, 256 threads, 4x4 per thread. M,N,K all divisible.
// ---------------------------------------------------------------------------
template <bool RELU>
__global__ __launch_bounds__(256) void gemm_bias_kernel(const float* __restrict__ A,
                                                        const float* __restrict__ W,
                                                        const float* __restrict__ bias,
                                                        float* __restrict__ C,
                                                        int M, int N, int K) {
  const int tid = threadIdx.x;
  const int m0  = blockIdx.y * 64;
  const int n0  = blockIdx.x * 64;

  __shared__ float As[16][65];
  __shared__ float Ws[16][64];

  const int tx = tid & 15;
  const int ty = tid >> 4;

  float acc[4][4] = {};

  for (int k0 = 0; k0 < K; k0 += 16) {
    #pragma unroll
    for (int i = 0; i < 4; ++i) {   // A tile: 64x16
      int t = i * 256 + tid;
      int m = t >> 4, k = t & 15;
      As[k][m] = A[(size_t)(m0 + m) * K + k0 + k];
    }
    #pragma unroll
    for (int i = 0; i < 4; ++i) {   // W tile: 16x64
      int t = i * 256 + tid;
      int k = t >> 6, n = t & 63;
      Ws[k][n] = W[(size_t)(k0 + k) * N + n0 + n];
    }
    __syncthreads();

    #pragma unroll
    for (int k = 0; k < 16; ++k) {
      float a[4], w[4];
      #pragma unroll
      for (int i = 0; i < 4; ++i) a[i] = As[k][ty * 4 + i];
      #pragma unroll
      for (int j = 0; j < 4; ++j) w[j] = Ws[k][tx * 4 + j];
      #pragma unroll
      for (int i = 0; i < 4; ++i)
        #pragma unroll
        for (int j = 0; j < 4; ++j)
          acc[i][j] += a[i] * w[j];
    }
    __syncthreads();
  }

  #pragma unroll
  for (int i = 0; i < 4; ++i) {
    int m = m0 + ty * 4 + i;
    float vb[4];
    #pragma unroll
    for (int j = 0; j < 4; ++j) {
      float x = acc[i][j] + bias[n0 + tx * 4 + j];
      if (RELU) x = fmaxf(x, 0.f);
      vb[j] = x;
    }
    *reinterpret_cast<float4*>(&C[(size_t)m * N + n0 + tx * 4]) =
        make_float4(vb[0], vb[1], vb[2], vb[3]);
  }
}

// ---------------------------------------------------------------------------
// Kernel 5: layer-3 GEMM (N=128) + bias + row L2-normalize -> d_out
// 32x128 tile per block, 256 threads, 4x4 per thread.
// ---------------------------------------------------------------------------
__global__ __launch_bounds__(256) void gemm3_norm_kernel(const float* __restrict__ A,
                                                         const float* __restrict__ W,
                                                         const float* __restrict__ bias,
                                                         float* __restrict__ out,
                                                         int M, int K) {
  const int N   = 128;
  const int tid = threadIdx.x;
  const int m0  = blockIdx.x * 32;

  __shared__ float As[16][33];
  __shared__ float Ws[16][128];

  const int tx = tid & 31;   // 32 column groups of 4
  const int ty = tid >> 5;   // 8 row groups of 4

  float acc[4][4] = {};

  for (int k0 = 0; k0 < K; k0 += 16) {
    #pragma unroll
    for (int i = 0; i < 2; ++i) {   // A tile: 32x16
      int t = i * 256 + tid;
      int m = t >> 4, k = t & 15;
      As[k][m] = A[(size_t)(m0 + m) * K + k0 + k];
    }
    #pragma unroll
    for (int i = 0; i < 8; ++i) {   // W tile: 16x128
      int t = i * 256 + tid;
      int k = t >> 7, n = t & 127;
      Ws[k][n] = W[(size_t)(k0 + k) * N + n];
    }
    __syncthreads();

    #pragma unroll
    for (int k = 0; k < 16; ++k) {
      float a[4], w[4];
      #pragma unroll
      for (int i = 0; i < 4; ++i) a[i] = As[k][ty * 4 + i];
      #pragma unroll
      for (int j = 0; j < 4; ++j) w[j] = Ws[k][tx * 4 + j];
      #pragma unroll
      for (int i = 0; i < 4; ++i)
        #pragma unroll
        for (int j = 0; j < 4; ++j)
          acc[i][j] += a[i] * w[j];
    }
    __syncthreads();
  }

  float val[4][4];
  float psq[4];
  #pragma unroll
  for (int i = 0; i < 4; ++i) {
    psq[i] = 0.f;
    #pragma unroll
    for (int j = 0; j < 4; ++j) {
      float x = acc[i][j] + bias[tx * 4 + j];
      val[i][j] = x;
      psq[i] += x * x;
    }
  }

  __shared__ float red[32][33];
  #pragma unroll
  for (int i = 0; i < 4; ++i) red[ty * 4 + i][tx] = psq[i];
  __syncthreads();

  __shared__ float rnorm[32];
  if (tid < 32) {
    float s = 0.f;
    #pragma unroll
    for (int t = 0; t < 32; ++t) s += red[tid][t];
    rnorm[tid] = 1.0f / sqrtf(fmaxf(s, 1e-12f));
  }
  __syncthreads();

  #pragma unroll
  for (int i = 0; i < 4; ++i) {
    int m = m0 + ty * 4 + i;
    float r = rnorm[ty * 4 + i];
    *reinterpret_cast<float4*>(&out[(size_t)m * N + tx * 4]) =
        make_float4(val[i][0] * r, val[i][1] * r, val[i][2] * r, val[i][3] * r);
  }
}

// ---------------------------------------------------------------------------
// kernel_launch
// ---------------------------------------------------------------------------
extern "C" void kernel_launch(void* const* d_in, const int* in_sizes, int n_in,
                              void* d_out, int out_size, void* d_ws, size_t ws_size,
                              hipStream_t stream) {
  const int*   idx[15];
  const float* tab[15];
  for (int i = 0; i < 15; ++i) {
    idx[i] = (const int*)d_in[i];
    tab[i] = (const float*)d_in[15 + i];
  }
  const float* cross_V = (const float*)d_in[30];
  const float* cross_U = (const float*)d_in[31];
  const float* cross_b = (const float*)d_in[32];
  const float* W1 = (const float*)d_in[33];
  const float* b1 = (const float*)d_in[34];
  const float* W2 = (const float*)d_in[35];
  const float* b2 = (const float*)d_in[36];
  const float* W3 = (const float*)d_in[37];
  const float* b3 = (const float*)d_in[38];
  float* out = (float*)d_out;

  // workspace layout: x0 [B,480] | h1 [B,512] | h2 [B,256]  (~10.2 MB total)
  float* x0 = (float*)d_ws;
  float* h1 = x0 + (size_t)NB * DIN;
  float* h2 = h1 + (size_t)NB * 512;

  SeqArgs sa;
  for (int i = 0; i < 9; ++i) { sa.idx[i] = idx[6 + i]; sa.tab[i] = tab[6 + i]; }
  ScalArgs ca;
  for (int i = 0; i < 6; ++i) { ca.idx[i] = idx[i]; ca.tab[i] = tab[i]; }

  hipLaunchKernelGGL(seq_pool_kernel, dim3(NB, 9), dim3(256), 0, stream, sa, x0);
  hipLaunchKernelGGL(scalar_gather_kernel, dim3((NB * 6 * NEMB + 255) / 256), dim3(256), 0, stream,
                     ca, x0);
  hipLaunchKernelGGL(cross_kernel, dim3(NB), dim3(64), 0, stream, x0, cross_V, cross_U, cross_b);
  hipLaunchKernelGGL((gemm_bias_kernel<true>), dim3(512 / 64, NB / 64), dim3(256), 0, stream,
                     x0, W1, b1, h1, NB, 512, DIN);
  hipLaunchKernelGGL((gemm_bias_kernel<true>), dim3(256 / 64, NB / 64), dim3(256), 0, stream,
                     h1, W2, b2, h2, NB, 256, 512);
  hipLaunchKernelGGL(gemm3_norm_kernel, dim3(NB / 32), dim3(256), 0, stream, h2, W3, b3, out,
                     NB, 256);
}

// Round 2
// 206.950 us; speedup vs baseline: 1.1206x; 1.1206x over previous
//
#include <hip/hip_runtime.h>
#include <cmath>

#define NB 2048
#define NL 375
#define NLP 384   // NL padded to 12*32
#define NEMB 32
#define DIN 480   // 15 * 32

// ---------------------------------------------------------------------------
// Kernel 1: sequence features — gather [B,L,32] and mean-pool over L -> x0
// One block per (batch row, feature). float4 loads: 8 lanes cover one 128B
// row -> one wave64 load instruction fetches 8 table rows (1 KB).
// Index buffer padded to 384 so the pool loop fully unrolls (12 iters),
// giving ~11 independent loads in flight per wave.
// ---------------------------------------------------------------------------
struct SeqArgs {
  const int*   idx[9];
  const float* tab[9];
};

__global__ __launch_bounds__(256) void seq_pool_kernel(SeqArgs args, float* __restrict__ x0) {
  const int b   = blockIdx.x;
  const int f   = blockIdx.y;
  const int tid = threadIdx.x;

  __shared__ int sidx[NLP];
  const int*   idx = args.idx[f];
  const float* tab = args.tab[f];

  // pad tail with a valid index (element 0); its contribution is masked out
  for (int i = tid; i < NLP; i += 256) sidx[i] = (i < NL) ? idx[b * NL + i] : idx[b * NL];
  __syncthreads();

  const int c = tid & 7;    // float4 column within the 32-float row
  const int s = tid >> 3;   // 0..31 slice over sequence positions

  const float4* tab4 = reinterpret_cast<const float4*>(tab);

  float4 acc = make_float4(0.f, 0.f, 0.f, 0.f);
  #pragma unroll
  for (int it = 0; it < 11; ++it) {            // l = s + it*32 < 352+31 < 375 always
    const int l = s + it * 32;
    float4 v = tab4[(size_t)sidx[l] * 8 + c];
    acc.x += v.x; acc.y += v.y; acc.z += v.z; acc.w += v.w;
  }
  {                                            // tail: l = s + 352, valid iff s < 23
    const int l = s + 352;
    float4 v = tab4[(size_t)sidx[l] * 8 + c];
    if (s < 23) { acc.x += v.x; acc.y += v.y; acc.z += v.z; acc.w += v.w; }
  }

  // wave-level reduce over the 8 s-slices within this wave (lane bits 3..5)
  #pragma unroll
  for (int off = 8; off <= 32; off <<= 1) {
    acc.x += __shfl_xor(acc.x, off, 64);
    acc.y += __shfl_xor(acc.y, off, 64);
    acc.z += __shfl_xor(acc.z, off, 64);
    acc.w += __shfl_xor(acc.w, off, 64);
  }

  __shared__ float4 wpart[4][8];
  const int wave = tid >> 6;
  const int lane = tid & 63;
  if (lane < 8) wpart[wave][lane] = acc;       // lane==c for lane<8
  __syncthreads();

  if (tid < 8) {
    float4 s0 = wpart[0][tid], s1 = wpart[1][tid], s2 = wpart[2][tid], s3 = wpart[3][tid];
    const float inv = 1.0f / (float)NL;
    float4 r;
    r.x = (s0.x + s1.x + s2.x + s3.x) * inv;
    r.y = (s0.y + s1.y + s2.y + s3.y) * inv;
    r.z = (s0.z + s1.z + s2.z + s3.z) * inv;
    r.w = (s0.w + s1.w + s2.w + s3.w) * inv;
    float* out = x0 + (size_t)b * DIN + (6 + f) * NEMB + tid * 4;
    *reinterpret_cast<float4*>(out) = r;
  }
}

// ---------------------------------------------------------------------------
// Kernel 2: scalar features — single-row gather -> x0
// ---------------------------------------------------------------------------
struct ScalArgs {
  const int*   idx[6];
  const float* tab[6];
};

__global__ __launch_bounds__(256) void scalar_gather_kernel(ScalArgs args, float* __restrict__ x0) {
  int e = blockIdx.x * 256 + threadIdx.x;   // total NB*6*32
  if (e >= NB * 6 * NEMB) return;
  int d = e & 31;
  int f = (e >> 5) % 6;
  int b = e / (6 * NEMB);
  int ix = args.idx[f][b];
  x0[(size_t)b * DIN + f * NEMB + d] = args.tab[f][(size_t)ix * NEMB + d];
}

// ---------------------------------------------------------------------------
// Kernel 3: DCN cross layer, in-place on x0. One wave per row.
// proj = (x0 @ V) @ U + b ;  x = x0 * proj + x0
// ---------------------------------------------------------------------------
__global__ __launch_bounds__(64) void cross_kernel(float* __restrict__ x0,
                                                   const float* __restrict__ V,
                                                   const float* __restrict__ U,
                                                   const float* __restrict__ bias) {
  const int b    = blockIdx.x;
  const int lane = threadIdx.x;
  float* row = x0 + (size_t)b * DIN;

  float xv[8];
  float t[5] = {0.f, 0.f, 0.f, 0.f, 0.f};
  #pragma unroll
  for (int i = 0; i < 8; ++i) {
    int j = lane + i * 64;
    if (j < DIN) {
      xv[i] = row[j];
      #pragma unroll
      for (int p = 0; p < 5; ++p) t[p] += xv[i] * V[j * 5 + p];
    } else {
      xv[i] = 0.f;
    }
  }
  #pragma unroll
  for (int p = 0; p < 5; ++p) {
    float v = t[p];
    for (int off = 32; off; off >>= 1) v += __shfl_xor(v, off, 64);
    t[p] = v;
  }
  #pragma unroll
  for (int i = 0; i < 8; ++i) {
    int j = lane + i * 64;
    if (j < DIN) {
      float proj = bias[j];
      #pragma unroll
      for (int p = 0; p < 5; ++p) proj += t[p] * U[p * DIN + j];
      row[j] = xv[i] * proj + xv[i];
    }
  }
}

// ---------------------------------------------------------------------------
// Kernel 4: fp32 tiled GEMM, C = relu?(A[M,K] @ W[K,N] + bias)
// 64x64 tile, BK=16, 256 threads, 4x4 per thread. M,N,K all divisible.
// ---------------------------------------------------------------------------
template <bool RELU>
__global__ __launch_bounds__(256) void gemm_bias_kernel(const float* __restrict__ A,
                                                        const float* __restrict__ W,
                                                        const float* __restrict__ bias,
                                                        float* __restrict__ C,
                                                        int M, int N, int K) {
  const int tid = threadIdx.x;
  const int m0  = blockIdx.y * 64;
  const int n0  = blockIdx.x * 64;

  __shared__ float As[16][65];
  __shared__ float Ws[16][64];

  const int tx = tid & 15;
  const int ty = tid >> 4;

  float acc[4][4] = {};

  for (int k0 = 0; k0 < K; k0 += 16) {
    #pragma unroll
    for (int i = 0; i < 4; ++i) {   // A tile: 64x16
      int t = i * 256 + tid;
      int m = t >> 4, k = t & 15;
      As[k][m] = A[(size_t)(m0 + m) * K + k0 + k];
    }
    #pragma unroll
    for (int i = 0; i < 4; ++i) {   // W tile: 16x64
      int t = i * 256 + tid;
      int k = t >> 6, n = t & 63;
      Ws[k][n] = W[(size_t)(k0 + k) * N + n0 + n];
    }
    __syncthreads();

    #pragma unroll
    for (int k = 0; k < 16; ++k) {
      float a[4], w[4];
      #pragma unroll
      for (int i = 0; i < 4; ++i) a[i] = As[k][ty * 4 + i];
      #pragma unroll
      for (int j = 0; j < 4; ++j) w[j] = Ws[k][tx * 4 + j];
      #pragma unroll
      for (int i = 0; i < 4; ++i)
        #pragma unroll
        for (int j = 0; j < 4; ++j)
          acc[i][j] += a[i] * w[j];
    }
    __syncthreads();
  }

  #pragma unroll
  for (int i = 0; i < 4; ++i) {
    int m = m0 + ty * 4 + i;
    float vb[4];
    #pragma unroll
    for (int j = 0; j < 4; ++j) {
      float x = acc[i][j] + bias[n0 + tx * 4 + j];
      if (RELU) x = fmaxf(x, 0.f);
      vb[j] = x;
    }
    *reinterpret_cast<float4*>(&C[(size_t)m * N + n0 + tx * 4]) =
        make_float4(vb[0], vb[1], vb[2], vb[3]);
  }
}

// ---------------------------------------------------------------------------
// Kernel 5: layer-3 GEMM (N=128) + bias + row L2-normalize -> d_out
// 32x128 tile per block, 256 threads, 4x4 per thread.
// ---------------------------------------------------------------------------
__global__ __launch_bounds__(256) void gemm3_norm_kernel(const float* __restrict__ A,
                                                         const float* __restrict__ W,
                                                         const float* __restrict__ bias,
                                                         float* __restrict__ out,
                                                         int M, int K) {
  const int N   = 128;
  const int tid = threadIdx.x;
  const int m0  = blockIdx.x * 32;

  __shared__ float As[16][33];
  __shared__ float Ws[16][128];

  const int tx = tid & 31;   // 32 column groups of 4
  const int ty = tid >> 5;   // 8 row groups of 4

  float acc[4][4] = {};

  for (int k0 = 0; k0 < K; k0 += 16) {
    #pragma unroll
    for (int i = 0; i < 2; ++i) {   // A tile: 32x16
      int t = i * 256 + tid;
      int m = t >> 4, k = t & 15;
      As[k][m] = A[(size_t)(m0 + m) * K + k0 + k];
    }
    #pragma unroll
    for (int i = 0; i < 8; ++i) {   // W tile: 16x128
      int t = i * 256 + tid;
      int k = t >> 7, n = t & 127;
      Ws[k][n] = W[(size_t)(k0 + k) * N + n];
    }
    __syncthreads();

    #pragma unroll
    for (int k = 0; k < 16; ++k) {
      float a[4], w[4];
      #pragma unroll
      for (int i = 0; i < 4; ++i) a[i] = As[k][ty * 4 + i];
      #pragma unroll
      for (int j = 0; j < 4; ++j) w[j] = Ws[k][tx * 4 + j];
      #pragma unroll
      for (int i = 0; i < 4; ++i)
        #pragma unroll
        for (int j = 0; j < 4; ++j)
          acc[i][j] += a[i] * w[j];
    }
    __syncthreads();
  }

  float val[4][4];
  float psq[4];
  #pragma unroll
  for (int i = 0; i < 4; ++i) {
    psq[i] = 0.f;
    #pragma unroll
    for (int j = 0; j < 4; ++j) {
      float x = acc[i][j] + bias[tx * 4 + j];
      val[i][j] = x;
      psq[i] += x * x;
    }
  }

  __shared__ float red[32][33];
  #pragma unroll
  for (int i = 0; i < 4; ++i) red[ty * 4 + i][tx] = psq[i];
  __syncthreads();

  __shared__ float rnorm[32];
  if (tid < 32) {
    float s = 0.f;
    #pragma unroll
    for (int t = 0; t < 32; ++t) s += red[tid][t];
    rnorm[tid] = 1.0f / sqrtf(fmaxf(s, 1e-12f));
  }
  __syncthreads();

  #pragma unroll
  for (int i = 0; i < 4; ++i) {
    int m = m0 + ty * 4 + i;
    float r = rnorm[ty * 4 + i];
    *reinterpret_cast<float4*>(&out[(size_t)m * N + tx * 4]) =
        make_float4(val[i][0] * r, val[i][1] * r, val[i][2] * r, val[i][3] * r);
  }
}

// ---------------------------------------------------------------------------
// kernel_launch
// ---------------------------------------------------------------------------
extern "C" void kernel_launch(void* const* d_in, const int* in_sizes, int n_in,
                              void* d_out, int out_size, void* d_ws, size_t ws_size,
                              hipStream_t stream) {
  const int*   idx[15];
  const float* tab[15];
  for (int i = 0; i < 15; ++i) {
    idx[i] = (const int*)d_in[i];
    tab[i] = (const float*)d_in[15 + i];
  }
  const float* cross_V = (const float*)d_in[30];
  const float* cross_U = (const float*)d_in[31];
  const float* cross_b = (const float*)d_in[32];
  const float* W1 = (const float*)d_in[33];
  const float* b1 = (const float*)d_in[34];
  const float* W2 = (const float*)d_in[35];
  const float* b2 = (const float*)d_in[36];
  const float* W3 = (const float*)d_in[37];
  const float* b3 = (const float*)d_in[38];
  float* out = (float*)d_out;

  // workspace layout: x0 [B,480] | h1 [B,512] | h2 [B,256]  (~10.2 MB total)
  float* x0 = (float*)d_ws;
  float* h1 = x0 + (size_t)NB * DIN;
  float* h2 = h1 + (size_t)NB * 512;

  SeqArgs sa;
  for (int i = 0; i < 9; ++i) { sa.idx[i] = idx[6 + i]; sa.tab[i] = tab[6 + i]; }
  ScalArgs ca;
  for (int i = 0; i < 6; ++i) { ca.idx[i] = idx[i]; ca.tab[i] = tab[i]; }

  hipLaunchKernelGGL(seq_pool_kernel, dim3(NB, 9), dim3(256), 0, stream, sa, x0);
  hipLaunchKernelGGL(scalar_gather_kernel, dim3((NB * 6 * NEMB + 255) / 256), dim3(256), 0, stream,
                     ca, x0);
  hipLaunchKernelGGL(cross_kernel, dim3(NB), dim3(64), 0, stream, x0, cross_V, cross_U, cross_b);
  hipLaunchKernelGGL((gemm_bias_kernel<true>), dim3(512 / 64, NB / 64), dim3(256), 0, stream,
                     x0, W1, b1, h1, NB, 512, DIN);
  hipLaunchKernelGGL((gemm_bias_kernel<true>), dim3(256 / 64, NB / 64), dim3(256), 0, stream,
                     h1, W2, b2, h2, NB, 256, 512);
  hipLaunchKernelGGL(gemm3_norm_kernel, dim3(NB / 32), dim3(256), 0, stream, h2, W3, b3, out,
                     NB, 256);
}

// Round 3
// 129.704 us; speedup vs baseline: 1.7880x; 1.5955x over previous
//
#include <hip/hip_runtime.h>
#include <cmath>

#define NB 2048
#define NL 375
#define NLP 384   // NL padded to 12*32
#define NEMB 32
#define DIN 480   // 15 * 32

typedef __attribute__((ext_vector_type(8))) short short8;
typedef __attribute__((ext_vector_type(4))) short short4v;
typedef __attribute__((ext_vector_type(4))) float f32x4;

__device__ inline short f2bf(float x) {
  union { float f; unsigned u; } v; v.f = x;
  unsigned r = v.u + 0x7fffu + ((v.u >> 16) & 1u);   // round-to-nearest-even
  return (short)(r >> 16);
}

// ---------------------------------------------------------------------------
// Kernel 1: sequence features — gather [B,L,32] and mean-pool over L -> x0
// (unchanged from round 2; latency/miss-bound)
// ---------------------------------------------------------------------------
struct SeqArgs {
  const int*   idx[9];
  const float* tab[9];
};

__global__ __launch_bounds__(256) void seq_pool_kernel(SeqArgs args, float* __restrict__ x0) {
  const int b   = blockIdx.x;
  const int f   = blockIdx.y;
  const int tid = threadIdx.x;

  __shared__ int sidx[NLP];
  const int*   idx = args.idx[f];
  const float* tab = args.tab[f];

  for (int i = tid; i < NLP; i += 256) sidx[i] = (i < NL) ? idx[b * NL + i] : idx[b * NL];
  __syncthreads();

  const int c = tid & 7;    // float4 column within the 32-float row
  const int s = tid >> 3;   // 0..31 slice over sequence positions

  const float4* tab4 = reinterpret_cast<const float4*>(tab);

  float4 acc = make_float4(0.f, 0.f, 0.f, 0.f);
  #pragma unroll
  for (int it = 0; it < 11; ++it) {
    const int l = s + it * 32;
    float4 v = tab4[(size_t)sidx[l] * 8 + c];
    acc.x += v.x; acc.y += v.y; acc.z += v.z; acc.w += v.w;
  }
  {
    const int l = s + 352;
    float4 v = tab4[(size_t)sidx[l] * 8 + c];
    if (s < 23) { acc.x += v.x; acc.y += v.y; acc.z += v.z; acc.w += v.w; }
  }

  #pragma unroll
  for (int off = 8; off <= 32; off <<= 1) {
    acc.x += __shfl_xor(acc.x, off, 64);
    acc.y += __shfl_xor(acc.y, off, 64);
    acc.z += __shfl_xor(acc.z, off, 64);
    acc.w += __shfl_xor(acc.w, off, 64);
  }

  __shared__ float4 wpart[4][8];
  const int wave = tid >> 6;
  const int lane = tid & 63;
  if (lane < 8) wpart[wave][lane] = acc;
  __syncthreads();

  if (tid < 8) {
    float4 s0 = wpart[0][tid], s1 = wpart[1][tid], s2 = wpart[2][tid], s3 = wpart[3][tid];
    const float inv = 1.0f / (float)NL;
    float4 r;
    r.x = (s0.x + s1.x + s2.x + s3.x) * inv;
    r.y = (s0.y + s1.y + s2.y + s3.y) * inv;
    r.z = (s0.z + s1.z + s2.z + s3.z) * inv;
    r.w = (s0.w + s1.w + s2.w + s3.w) * inv;
    float* out = x0 + (size_t)b * DIN + (6 + f) * NEMB + tid * 4;
    *reinterpret_cast<float4*>(out) = r;
  }
}

// ---------------------------------------------------------------------------
// Kernel 2: fused scalar-gather + DCN cross layer. One wave per row.
// Gathers the 6 scalar features (j<192), reads pooled seq part (j>=192) from
// x0, computes proj = (x @ V) @ U + b, writes x0 = x*proj + x.
// ---------------------------------------------------------------------------
struct ScalArgs {
  const int*   idx[6];
  const float* tab[6];
};

__global__ __launch_bounds__(64) void cross_scalar_kernel(ScalArgs args,
                                                          float* __restrict__ x0,
                                                          const float* __restrict__ V,
                                                          const float* __restrict__ U,
                                                          const float* __restrict__ bias) {
  const int b    = blockIdx.x;
  const int lane = threadIdx.x;
  float* row = x0 + (size_t)b * DIN;

  float xv[8];
  float t[5] = {0.f, 0.f, 0.f, 0.f, 0.f};
  #pragma unroll
  for (int i = 0; i < 8; ++i) {
    int j = lane + i * 64;
    float x;
    if (i < 3) {                       // scalar-feature region: j in [0,192)
      int f = j >> 5, d = j & 31;
      x = args.tab[f][(size_t)args.idx[f][b] * NEMB + d];
    } else if (j < DIN) {              // pooled seq region from x0
      x = row[j];
    } else {
      x = 0.f;
    }
    xv[i] = x;
    if (j < DIN) {
      #pragma unroll
      for (int p = 0; p < 5; ++p) t[p] += x * V[j * 5 + p];
    }
  }
  #pragma unroll
  for (int p = 0; p < 5; ++p) {
    float v = t[p];
    for (int off = 32; off; off >>= 1) v += __shfl_xor(v, off, 64);
    t[p] = v;
  }
  #pragma unroll
  for (int i = 0; i < 8; ++i) {
    int j = lane + i * 64;
    if (j < DIN) {
      float proj = bias[j];
      #pragma unroll
      for (int p = 0; p < 5; ++p) proj += t[p] * U[p * DIN + j];
      row[j] = xv[i] * proj + xv[i];
    }
  }
}

// ---------------------------------------------------------------------------
// Kernel 3: bf16-MFMA GEMM, C = relu?(A[M,K] @ W[K,N] + bias)
// Block 64x64, 4 waves (each a 32x32 quadrant = 2x2 16x16 frags), BK=32.
// fp32 -> bf16 RNE conversion during LDS staging. LDS rows padded to 40
// shorts (80B) -> ~2-way bank conflicts on b128 ops.
// Fragment layout (m92-verified family): A/B lane&15 = row(m)/col(n),
// k = (lane>>4)*8 + elem; C/D col = lane&15, row = (lane>>4)*4 + reg.
// ---------------------------------------------------------------------------
template <bool RELU>
__global__ __launch_bounds__(256) void gemm_mfma_kernel(const float* __restrict__ A,
                                                        const float* __restrict__ W,
                                                        const float* __restrict__ bias,
                                                        float* __restrict__ C,
                                                        int M, int N, int K) {
  const int tid  = threadIdx.x;
  const int m0   = blockIdx.y * 64;
  const int n0   = blockIdx.x * 64;
  const int wave = tid >> 6;
  const int lane = tid & 63;
  const int wm   = wave >> 1;
  const int wn   = wave & 1;

  __shared__ short As[64][40];   // [m][k], bf16 bits
  __shared__ short Bs[64][40];   // [n][k], bf16 bits (W transposed in LDS)

  f32x4 acc[2][2];
  #pragma unroll
  for (int i = 0; i < 2; ++i)
    #pragma unroll
    for (int j = 0; j < 2; ++j)
      acc[i][j] = (f32x4){0.f, 0.f, 0.f, 0.f};

  const int am  = tid >> 2;   // 0..63
  const int akq = tid & 3;    // k chunk of 8
  const int bn  = tid & 63;   // 0..63
  const int bkg = tid >> 6;   // k chunk of 8

  for (int k0 = 0; k0 < K; k0 += 32) {
    // A tile: 64 rows x 32 k. Each thread: 8 contiguous k of one row.
    {
      const float* ap = A + (size_t)(m0 + am) * K + k0 + akq * 8;
      float4 a0 = *reinterpret_cast<const float4*>(ap);
      float4 a1 = *reinterpret_cast<const float4*>(ap + 4);
      short8 av = { f2bf(a0.x), f2bf(a0.y), f2bf(a0.z), f2bf(a0.w),
                    f2bf(a1.x), f2bf(a1.y), f2bf(a1.z), f2bf(a1.w) };
      *reinterpret_cast<short8*>(&As[am][akq * 8]) = av;
    }
    // B tile: 64 n x 32 k, transposed into Bs[n][k]. Coalesced along n.
    {
      float bv[8];
      #pragma unroll
      for (int i = 0; i < 8; ++i)
        bv[i] = W[(size_t)(k0 + bkg * 8 + i) * N + n0 + bn];
      short8 wv = { f2bf(bv[0]), f2bf(bv[1]), f2bf(bv[2]), f2bf(bv[3]),
                    f2bf(bv[4]), f2bf(bv[5]), f2bf(bv[6]), f2bf(bv[7]) };
      *reinterpret_cast<short8*>(&Bs[bn][bkg * 8]) = wv;
    }
    __syncthreads();

    short8 bf[2];
    #pragma unroll
    for (int fn = 0; fn < 2; ++fn)
      bf[fn] = *reinterpret_cast<const short8*>(&Bs[wn * 32 + fn * 16 + (lane & 15)][(lane >> 4) * 8]);
    #pragma unroll
    for (int fm = 0; fm < 2; ++fm) {
      short8 af = *reinterpret_cast<const short8*>(&As[wm * 32 + fm * 16 + (lane & 15)][(lane >> 4) * 8]);
      #pragma unroll
      for (int fn = 0; fn < 2; ++fn)
        acc[fm][fn] = __builtin_amdgcn_mfma_f32_16x16x32_bf16(af, bf[fn], acc[fm][fn], 0, 0, 0);
    }
    __syncthreads();
  }

  #pragma unroll
  for (int fm = 0; fm < 2; ++fm) {
    #pragma unroll
    for (int fn = 0; fn < 2; ++fn) {
      const int col  = n0 + wn * 32 + fn * 16 + (lane & 15);
      const float bc = bias[col];
      #pragma unroll
      for (int r = 0; r < 4; ++r) {
        const int m = m0 + wm * 32 + fm * 16 + (lane >> 4) * 4 + r;
        float x = acc[fm][fn][r] + bc;
        if (RELU) x = fmaxf(x, 0.f);
        C[(size_t)m * N + col] = x;
      }
    }
  }
}

// ---------------------------------------------------------------------------
// Kernel 4: layer-3 bf16-MFMA GEMM (N=128) + bias + row L2-normalize -> out
// Block 32x128, 4 waves (wave w covers cols w*32; 2x2 frags), BK=32.
// ---------------------------------------------------------------------------
__global__ __launch_bounds__(256) void gemm3_norm_kernel(const float* __restrict__ A,
                                                         const float* __restrict__ W,
                                                         const float* __restrict__ bias,
                                                         float* __restrict__ out,
                                                         int M, int K) {
  const int N    = 128;
  const int tid  = threadIdx.x;
  const int m0   = blockIdx.x * 32;
  const int wave = tid >> 6;
  const int lane = tid & 63;

  __shared__ short As[32][40];    // [m][k]
  __shared__ short Bs[128][40];   // [n][k]

  f32x4 acc[2][2];
  #pragma unroll
  for (int i = 0; i < 2; ++i)
    #pragma unroll
    for (int j = 0; j < 2; ++j)
      acc[i][j] = (f32x4){0.f, 0.f, 0.f, 0.f};

  const int am  = tid >> 3;   // 0..31
  const int akq = tid & 7;    // k chunk of 4
  const int bn  = tid & 127;  // 0..127
  const int bkg = tid >> 7;   // k chunk of 16

  for (int k0 = 0; k0 < K; k0 += 32) {
    {
      float4 a0 = *reinterpret_cast<const float4*>(A + (size_t)(m0 + am) * K + k0 + akq * 4);
      short4v av = { f2bf(a0.x), f2bf(a0.y), f2bf(a0.z), f2bf(a0.w) };
      *reinterpret_cast<short4v*>(&As[am][akq * 4]) = av;
    }
    {
      float bv[16];
      #pragma unroll
      for (int i = 0; i < 16; ++i)
        bv[i] = W[(size_t)(k0 + bkg * 16 + i) * N + bn];
      short8 w0 = { f2bf(bv[0]),  f2bf(bv[1]),  f2bf(bv[2]),  f2bf(bv[3]),
                    f2bf(bv[4]),  f2bf(bv[5]),  f2bf(bv[6]),  f2bf(bv[7]) };
      short8 w1 = { f2bf(bv[8]),  f2bf(bv[9]),  f2bf(bv[10]), f2bf(bv[11]),
                    f2bf(bv[12]), f2bf(bv[13]), f2bf(bv[14]), f2bf(bv[15]) };
      *reinterpret_cast<short8*>(&Bs[bn][bkg * 16])     = w0;
      *reinterpret_cast<short8*>(&Bs[bn][bkg * 16 + 8]) = w1;
    }
    __syncthreads();

    short8 bf[2];
    #pragma unroll
    for (int fn = 0; fn < 2; ++fn)
      bf[fn] = *reinterpret_cast<const short8*>(&Bs[wave * 32 + fn * 16 + (lane & 15)][(lane >> 4) * 8]);
    #pragma unroll
    for (int fm = 0; fm < 2; ++fm) {
      short8 af = *reinterpret_cast<const short8*>(&As[fm * 16 + (lane & 15)][(lane >> 4) * 8]);
      #pragma unroll
      for (int fn = 0; fn < 2; ++fn)
        acc[fm][fn] = __builtin_amdgcn_mfma_f32_16x16x32_bf16(af, bf[fn], acc[fm][fn], 0, 0, 0);
    }
    __syncthreads();
  }

  // bias + partial square sums
  float val[2][2][4];
  float psq[2][4] = {};
  #pragma unroll
  for (int fm = 0; fm < 2; ++fm)
    #pragma unroll
    for (int fn = 0; fn < 2; ++fn) {
      const int col  = wave * 32 + fn * 16 + (lane & 15);
      const float bc = bias[col];
      #pragma unroll
      for (int r = 0; r < 4; ++r) {
        float x = acc[fm][fn][r] + bc;
        val[fm][fn][r] = x;
        psq[fm][r] += x * x;
      }
    }

  // reduce over the 16 columns held by lanes sharing lane>>4
  #pragma unroll
  for (int off = 1; off < 16; off <<= 1)
    #pragma unroll
    for (int fm = 0; fm < 2; ++fm)
      #pragma unroll
      for (int r = 0; r < 4; ++r)
        psq[fm][r] += __shfl_xor(psq[fm][r], off, 64);

  __shared__ float part[4][32];
  if ((lane & 15) == 0) {
    #pragma unroll
    for (int fm = 0; fm < 2; ++fm)
      #pragma unroll
      for (int r = 0; r < 4; ++r)
        part[wave][fm * 16 + (lane >> 4) * 4 + r] = psq[fm][r];
  }
  __syncthreads();

  __shared__ float rn[32];
  if (tid < 32)
    rn[tid] = 1.0f / sqrtf(fmaxf(part[0][tid] + part[1][tid] + part[2][tid] + part[3][tid], 1e-12f));
  __syncthreads();

  #pragma unroll
  for (int fm = 0; fm < 2; ++fm)
    #pragma unroll
    for (int fn = 0; fn < 2; ++fn) {
      const int col = wave * 32 + fn * 16 + (lane & 15);
      #pragma unroll
      for (int r = 0; r < 4; ++r) {
        const int mrow = fm * 16 + (lane >> 4) * 4 + r;
        out[(size_t)(m0 + mrow) * N + col] = val[fm][fn][r] * rn[mrow];
      }
    }
}

// ---------------------------------------------------------------------------
// kernel_launch
// ---------------------------------------------------------------------------
extern "C" void kernel_launch(void* const* d_in, const int* in_sizes, int n_in,
                              void* d_out, int out_size, void* d_ws, size_t ws_size,
                              hipStream_t stream) {
  const int*   idx[15];
  const float* tab[15];
  for (int i = 0; i < 15; ++i) {
    idx[i] = (const int*)d_in[i];
    tab[i] = (const float*)d_in[15 + i];
  }
  const float* cross_V = (const float*)d_in[30];
  const float* cross_U = (const float*)d_in[31];
  const float* cross_b = (const float*)d_in[32];
  const float* W1 = (const float*)d_in[33];
  const float* b1 = (const float*)d_in[34];
  const float* W2 = (const float*)d_in[35];
  const float* b2 = (const float*)d_in[36];
  const float* W3 = (const float*)d_in[37];
  const float* b3 = (const float*)d_in[38];
  float* out = (float*)d_out;

  // workspace: x0 [B,480] | h1 [B,512] | h2 [B,256]  (~10.2 MB)
  float* x0 = (float*)d_ws;
  float* h1 = x0 + (size_t)NB * DIN;
  float* h2 = h1 + (size_t)NB * 512;

  SeqArgs sa;
  for (int i = 0; i < 9; ++i) { sa.idx[i] = idx[6 + i]; sa.tab[i] = tab[6 + i]; }
  ScalArgs ca;
  for (int i = 0; i < 6; ++i) { ca.idx[i] = idx[i]; ca.tab[i] = tab[i]; }

  hipLaunchKernelGGL(seq_pool_kernel, dim3(NB, 9), dim3(256), 0, stream, sa, x0);
  hipLaunchKernelGGL(cross_scalar_kernel, dim3(NB), dim3(64), 0, stream,
                     ca, x0, cross_V, cross_U, cross_b);
  hipLaunchKernelGGL((gemm_mfma_kernel<true>), dim3(512 / 64, NB / 64), dim3(256), 0, stream,
                     x0, W1, b1, h1, NB, 512, DIN);
  hipLaunchKernelGGL((gemm_mfma_kernel<true>), dim3(256 / 64, NB / 64), dim3(256), 0, stream,
                     h1, W2, b2, h2, NB, 256, 512);
  hipLaunchKernelGGL(gemm3_norm_kernel, dim3(NB / 32), dim3(256), 0, stream,
                     h2, W3, b3, out, NB, 256);
}

// Round 4
// 117.482 us; speedup vs baseline: 1.9740x; 1.1040x over previous
//
#include <hip/hip_runtime.h>
#include <cmath>

#define NB 2048
#define NL 375
#define NLP 384   // NL padded to 12*32
#define NEMB 32
#define DIN 480   // 15 * 32

typedef __attribute__((ext_vector_type(8))) short short8;
typedef __attribute__((ext_vector_type(4))) short short4v;
typedef __attribute__((ext_vector_type(4))) float f32x4;

__device__ inline short f2bf(float x) {
  union { float f; unsigned u; } v; v.f = x;
  unsigned r = v.u + 0x7fffu + ((v.u >> 16) & 1u);   // round-to-nearest-even
  return (short)(r >> 16);
}

// ---------------------------------------------------------------------------
// Kernel 1: sequence features — gather [B,L,32] and mean-pool over L -> x0
// Flat grid with FEATURE VARYING FASTEST (bid%9): each CU's resident blocks
// mix big-table (miss-bound) and tiny-table (L1-hit) features, so tiny-table
// compute hides under the MSHR-capped big-table miss stream instead of
// running as separate serial phases.
// ---------------------------------------------------------------------------
struct SeqArgs {
  const int*   idx[9];
  const float* tab[9];
};

__global__ __launch_bounds__(256) void seq_pool_kernel(SeqArgs args, float* __restrict__ x0) {
  const int bid = blockIdx.x;
  const int f   = bid % 9;   // feature fastest among consecutive blocks
  const int b   = bid / 9;
  const int tid = threadIdx.x;

  __shared__ int sidx[NLP];
  const int*   idx = args.idx[f];
  const float* tab = args.tab[f];

  for (int i = tid; i < NLP; i += 256) sidx[i] = (i < NL) ? idx[b * NL + i] : idx[b * NL];
  __syncthreads();

  const int c = tid & 7;    // float4 column within the 32-float row
  const int s = tid >> 3;   // 0..31 slice over sequence positions

  const float4* tab4 = reinterpret_cast<const float4*>(tab);

  float4 acc = make_float4(0.f, 0.f, 0.f, 0.f);
  #pragma unroll
  for (int it = 0; it < 11; ++it) {
    const int l = s + it * 32;
    float4 v = tab4[(size_t)sidx[l] * 8 + c];
    acc.x += v.x; acc.y += v.y; acc.z += v.z; acc.w += v.w;
  }
  {
    const int l = s + 352;
    float4 v = tab4[(size_t)sidx[l] * 8 + c];
    if (s < 23) { acc.x += v.x; acc.y += v.y; acc.z += v.z; acc.w += v.w; }
  }

  #pragma unroll
  for (int off = 8; off <= 32; off <<= 1) {
    acc.x += __shfl_xor(acc.x, off, 64);
    acc.y += __shfl_xor(acc.y, off, 64);
    acc.z += __shfl_xor(acc.z, off, 64);
    acc.w += __shfl_xor(acc.w, off, 64);
  }

  __shared__ float4 wpart[4][8];
  const int wave = tid >> 6;
  const int lane = tid & 63;
  if (lane < 8) wpart[wave][lane] = acc;
  __syncthreads();

  if (tid < 8) {
    float4 s0 = wpart[0][tid], s1 = wpart[1][tid], s2 = wpart[2][tid], s3 = wpart[3][tid];
    const float inv = 1.0f / (float)NL;
    float4 r;
    r.x = (s0.x + s1.x + s2.x + s3.x) * inv;
    r.y = (s0.y + s1.y + s2.y + s3.y) * inv;
    r.z = (s0.z + s1.z + s2.z + s3.z) * inv;
    r.w = (s0.w + s1.w + s2.w + s3.w) * inv;
    float* out = x0 + (size_t)b * DIN + (6 + f) * NEMB + tid * 4;
    *reinterpret_cast<float4*>(out) = r;
  }
}

// ---------------------------------------------------------------------------
// Kernel 2: fused scalar-gather + DCN cross layer. One wave per row.
// ---------------------------------------------------------------------------
struct ScalArgs {
  const int*   idx[6];
  const float* tab[6];
};

__global__ __launch_bounds__(64) void cross_scalar_kernel(ScalArgs args,
                                                          float* __restrict__ x0,
                                                          const float* __restrict__ V,
                                                          const float* __restrict__ U,
                                                          const float* __restrict__ bias) {
  const int b    = blockIdx.x;
  const int lane = threadIdx.x;
  float* row = x0 + (size_t)b * DIN;

  float xv[8];
  float t[5] = {0.f, 0.f, 0.f, 0.f, 0.f};
  #pragma unroll
  for (int i = 0; i < 8; ++i) {
    int j = lane + i * 64;
    float x;
    if (i < 3) {                       // scalar-feature region: j in [0,192)
      int f = j >> 5, d = j & 31;
      x = args.tab[f][(size_t)args.idx[f][b] * NEMB + d];
    } else if (j < DIN) {              // pooled seq region from x0
      x = row[j];
    } else {
      x = 0.f;
    }
    xv[i] = x;
    if (j < DIN) {
      #pragma unroll
      for (int p = 0; p < 5; ++p) t[p] += x * V[j * 5 + p];
    }
  }
  #pragma unroll
  for (int p = 0; p < 5; ++p) {
    float v = t[p];
    for (int off = 32; off; off >>= 1) v += __shfl_xor(v, off, 64);
    t[p] = v;
  }
  #pragma unroll
  for (int i = 0; i < 8; ++i) {
    int j = lane + i * 64;
    if (j < DIN) {
      float proj = bias[j];
      #pragma unroll
      for (int p = 0; p < 5; ++p) proj += t[p] * U[p * DIN + j];
      row[j] = xv[i] * proj + xv[i];
    }
  }
}

// ---------------------------------------------------------------------------
// Kernel 3: bf16-MFMA GEMM, C = relu?(A[M,K] @ W[K,N] + bias)
// Block 64x64, 4 waves (each a 32x32 quadrant = 2x2 16x16 frags), BK=32.
// ---------------------------------------------------------------------------
template <bool RELU>
__global__ __launch_bounds__(256) void gemm_mfma_kernel(const float* __restrict__ A,
                                                        const float* __restrict__ W,
                                                        const float* __restrict__ bias,
                                                        float* __restrict__ C,
                                                        int M, int N, int K) {
  const int tid  = threadIdx.x;
  const int m0   = blockIdx.y * 64;
  const int n0   = blockIdx.x * 64;
  const int wave = tid >> 6;
  const int lane = tid & 63;
  const int wm   = wave >> 1;
  const int wn   = wave & 1;

  __shared__ short As[64][40];   // [m][k], bf16 bits
  __shared__ short Bs[64][40];   // [n][k], bf16 bits (W transposed in LDS)

  f32x4 acc[2][2];
  #pragma unroll
  for (int i = 0; i < 2; ++i)
    #pragma unroll
    for (int j = 0; j < 2; ++j)
      acc[i][j] = (f32x4){0.f, 0.f, 0.f, 0.f};

  const int am  = tid >> 2;   // 0..63
  const int akq = tid & 3;    // k chunk of 8
  const int bn  = tid & 63;   // 0..63
  const int bkg = tid >> 6;   // k chunk of 8

  for (int k0 = 0; k0 < K; k0 += 32) {
    {
      const float* ap = A + (size_t)(m0 + am) * K + k0 + akq * 8;
      float4 a0 = *reinterpret_cast<const float4*>(ap);
      float4 a1 = *reinterpret_cast<const float4*>(ap + 4);
      short8 av = { f2bf(a0.x), f2bf(a0.y), f2bf(a0.z), f2bf(a0.w),
                    f2bf(a1.x), f2bf(a1.y), f2bf(a1.z), f2bf(a1.w) };
      *reinterpret_cast<short8*>(&As[am][akq * 8]) = av;
    }
    {
      float bv[8];
      #pragma unroll
      for (int i = 0; i < 8; ++i)
        bv[i] = W[(size_t)(k0 + bkg * 8 + i) * N + n0 + bn];
      short8 wv = { f2bf(bv[0]), f2bf(bv[1]), f2bf(bv[2]), f2bf(bv[3]),
                    f2bf(bv[4]), f2bf(bv[5]), f2bf(bv[6]), f2bf(bv[7]) };
      *reinterpret_cast<short8*>(&Bs[bn][bkg * 8]) = wv;
    }
    __syncthreads();

    short8 bf[2];
    #pragma unroll
    for (int fn = 0; fn < 2; ++fn)
      bf[fn] = *reinterpret_cast<const short8*>(&Bs[wn * 32 + fn * 16 + (lane & 15)][(lane >> 4) * 8]);
    #pragma unroll
    for (int fm = 0; fm < 2; ++fm) {
      short8 af = *reinterpret_cast<const short8*>(&As[wm * 32 + fm * 16 + (lane & 15)][(lane >> 4) * 8]);
      #pragma unroll
      for (int fn = 0; fn < 2; ++fn)
        acc[fm][fn] = __builtin_amdgcn_mfma_f32_16x16x32_bf16(af, bf[fn], acc[fm][fn], 0, 0, 0);
    }
    __syncthreads();
  }

  #pragma unroll
  for (int fm = 0; fm < 2; ++fm) {
    #pragma unroll
    for (int fn = 0; fn < 2; ++fn) {
      const int col  = n0 + wn * 32 + fn * 16 + (lane & 15);
      const float bc = bias[col];
      #pragma unroll
      for (int r = 0; r < 4; ++r) {
        const int m = m0 + wm * 32 + fm * 16 + (lane >> 4) * 4 + r;
        float x = acc[fm][fn][r] + bc;
        if (RELU) x = fmaxf(x, 0.f);
        C[(size_t)m * N + col] = x;
      }
    }
  }
}

// ---------------------------------------------------------------------------
// Kernel 4: layer-3 bf16-MFMA GEMM (N=128) + bias + row L2-normalize -> out
// ---------------------------------------------------------------------------
__global__ __launch_bounds__(256) void gemm3_norm_kernel(const float* __restrict__ A,
                                                         const float* __restrict__ W,
                                                         const float* __restrict__ bias,
                                                         float* __restrict__ out,
                                                         int M, int K) {
  const int N    = 128;
  const int tid  = threadIdx.x;
  const int m0   = blockIdx.x * 32;
  const int wave = tid >> 6;
  const int lane = tid & 63;

  __shared__ short As[32][40];    // [m][k]
  __shared__ short Bs[128][40];   // [n][k]

  f32x4 acc[2][2];
  #pragma unroll
  for (int i = 0; i < 2; ++i)
    #pragma unroll
    for (int j = 0; j < 2; ++j)
      acc[i][j] = (f32x4){0.f, 0.f, 0.f, 0.f};

  const int am  = tid >> 3;   // 0..31
  const int akq = tid & 7;    // k chunk of 4
  const int bn  = tid & 127;  // 0..127
  const int bkg = tid >> 7;   // k chunk of 16

  for (int k0 = 0; k0 < K; k0 += 32) {
    {
      float4 a0 = *reinterpret_cast<const float4*>(A + (size_t)(m0 + am) * K + k0 + akq * 4);
      short4v av = { f2bf(a0.x), f2bf(a0.y), f2bf(a0.z), f2bf(a0.w) };
      *reinterpret_cast<short4v*>(&As[am][akq * 4]) = av;
    }
    {
      float bv[16];
      #pragma unroll
      for (int i = 0; i < 16; ++i)
        bv[i] = W[(size_t)(k0 + bkg * 16 + i) * N + bn];
      short8 w0 = { f2bf(bv[0]),  f2bf(bv[1]),  f2bf(bv[2]),  f2bf(bv[3]),
                    f2bf(bv[4]),  f2bf(bv[5]),  f2bf(bv[6]),  f2bf(bv[7]) };
      short8 w1 = { f2bf(bv[8]),  f2bf(bv[9]),  f2bf(bv[10]), f2bf(bv[11]),
                    f2bf(bv[12]), f2bf(bv[13]), f2bf(bv[14]), f2bf(bv[15]) };
      *reinterpret_cast<short8*>(&Bs[bn][bkg * 16])     = w0;
      *reinterpret_cast<short8*>(&Bs[bn][bkg * 16 + 8]) = w1;
    }
    __syncthreads();

    short8 bf[2];
    #pragma unroll
    for (int fn = 0; fn < 2; ++fn)
      bf[fn] = *reinterpret_cast<const short8*>(&Bs[wave * 32 + fn * 16 + (lane & 15)][(lane >> 4) * 8]);
    #pragma unroll
    for (int fm = 0; fm < 2; ++fm) {
      short8 af = *reinterpret_cast<const short8*>(&As[fm * 16 + (lane & 15)][(lane >> 4) * 8]);
      #pragma unroll
      for (int fn = 0; fn < 2; ++fn)
        acc[fm][fn] = __builtin_amdgcn_mfma_f32_16x16x32_bf16(af, bf[fn], acc[fm][fn], 0, 0, 0);
    }
    __syncthreads();
  }

  float val[2][2][4];
  float psq[2][4] = {};
  #pragma unroll
  for (int fm = 0; fm < 2; ++fm)
    #pragma unroll
    for (int fn = 0; fn < 2; ++fn) {
      const int col  = wave * 32 + fn * 16 + (lane & 15);
      const float bc = bias[col];
      #pragma unroll
      for (int r = 0; r < 4; ++r) {
        float x = acc[fm][fn][r] + bc;
        val[fm][fn][r] = x;
        psq[fm][r] += x * x;
      }
    }

  #pragma unroll
  for (int off = 1; off < 16; off <<= 1)
    #pragma unroll
    for (int fm = 0; fm < 2; ++fm)
      #pragma unroll
      for (int r = 0; r < 4; ++r)
        psq[fm][r] += __shfl_xor(psq[fm][r], off, 64);

  __shared__ float part[4][32];
  if ((lane & 15) == 0) {
    #pragma unroll
    for (int fm = 0; fm < 2; ++fm)
      #pragma unroll
      for (int r = 0; r < 4; ++r)
        part[wave][fm * 16 + (lane >> 4) * 4 + r] = psq[fm][r];
  }
  __syncthreads();

  __shared__ float rn[32];
  if (tid < 32)
    rn[tid] = 1.0f / sqrtf(fmaxf(part[0][tid] + part[1][tid] + part[2][tid] + part[3][tid], 1e-12f));
  __syncthreads();

  #pragma unroll
  for (int fm = 0; fm < 2; ++fm)
    #pragma unroll
    for (int fn = 0; fn < 2; ++fn) {
      const int col = wave * 32 + fn * 16 + (lane & 15);
      #pragma unroll
      for (int r = 0; r < 4; ++r) {
        const int mrow = fm * 16 + (lane >> 4) * 4 + r;
        out[(size_t)(m0 + mrow) * N + col] = val[fm][fn][r] * rn[mrow];
      }
    }
}

// ---------------------------------------------------------------------------
// kernel_launch
// ---------------------------------------------------------------------------
extern "C" void kernel_launch(void* const* d_in, const int* in_sizes, int n_in,
                              void* d_out, int out_size, void* d_ws, size_t ws_size,
                              hipStream_t stream) {
  const int*   idx[15];
  const float* tab[15];
  for (int i = 0; i < 15; ++i) {
    idx[i] = (const int*)d_in[i];
    tab[i] = (const float*)d_in[15 + i];
  }
  const float* cross_V = (const float*)d_in[30];
  const float* cross_U = (const float*)d_in[31];
  const float* cross_b = (const float*)d_in[32];
  const float* W1 = (const float*)d_in[33];
  const float* b1 = (const float*)d_in[34];
  const float* W2 = (const float*)d_in[35];
  const float* b2 = (const float*)d_in[36];
  const float* W3 = (const float*)d_in[37];
  const float* b3 = (const float*)d_in[38];
  float* out = (float*)d_out;

  // workspace: x0 [B,480] | h1 [B,512] | h2 [B,256]  (~10.2 MB)
  float* x0 = (float*)d_ws;
  float* h1 = x0 + (size_t)NB * DIN;
  float* h2 = h1 + (size_t)NB * 512;

  SeqArgs sa;
  for (int i = 0; i < 9; ++i) { sa.idx[i] = idx[6 + i]; sa.tab[i] = tab[6 + i]; }
  ScalArgs ca;
  for (int i = 0; i < 6; ++i) { ca.idx[i] = idx[i]; ca.tab[i] = tab[i]; }

  hipLaunchKernelGGL(seq_pool_kernel, dim3(NB * 9), dim3(256), 0, stream, sa, x0);
  hipLaunchKernelGGL(cross_scalar_kernel, dim3(NB), dim3(64), 0, stream,
                     ca, x0, cross_V, cross_U, cross_b);
  hipLaunchKernelGGL((gemm_mfma_kernel<true>), dim3(512 / 64, NB / 64), dim3(256), 0, stream,
                     x0, W1, b1, h1, NB, 512, DIN);
  hipLaunchKernelGGL((gemm_mfma_kernel<true>), dim3(256 / 64, NB / 64), dim3(256), 0, stream,
                     h1, W2, b2, h2, NB, 256, 512);
  hipLaunchKernelGGL(gemm3_norm_kernel, dim3(NB / 32), dim3(256), 0, stream,
                     h2, W3, b3, out, NB, 256);
}

// Round 5
// 110.691 us; speedup vs baseline: 2.0951x; 1.0614x over previous
//
#include <hip/hip_runtime.h>
#include <cmath>

#define NB 2048
#define NL 375
#define NLP 384   // NL padded to 12*32
#define NEMB 32
#define DIN 480   // 15 * 32

typedef __attribute__((ext_vector_type(8))) short short8;
typedef __attribute__((ext_vector_type(4))) short short4v;
typedef __attribute__((ext_vector_type(4))) float f32x4;

__device__ inline short f2bf(float x) {
  union { float f; unsigned u; } v; v.f = x;
  unsigned r = v.u + 0x7fffu + ((v.u >> 16) & 1u);   // round-to-nearest-even
  return (short)(r >> 16);
}

// ---------------------------------------------------------------------------
// Kernel 1: sequence features — gather [B,L,32] and mean-pool over L -> x0
// Flat grid, feature varying fastest (bid%9) so each CU mixes big-table
// (miss-bound) and tiny-table (L1-hit) blocks.
// NT experiment: the two 1M-row tables (seq features 1,2 = track_uri_pl,
// track_name_pl; 137 MB unique lines/pass) are loaded with non-temporal
// hints so they don't allocate in L3. Goal: retained L3 working set drops
// from ~270 MB (> 256 MB capacity -> thrash) to ~133 MB, letting
// artist_name/album_name/indices stay L3-resident across graph replays.
// ---------------------------------------------------------------------------
struct SeqArgs {
  const int*   idx[9];
  const float* tab[9];
};

template <bool NT>
__device__ inline float4 gather_pool_body(const float* __restrict__ tab,
                                          const int* __restrict__ sidx,
                                          int s, int c) {
  const f32x4* tab4 = reinterpret_cast<const f32x4*>(tab);
  f32x4 acc = {0.f, 0.f, 0.f, 0.f};
  #pragma unroll
  for (int it = 0; it < 11; ++it) {
    const int l = s + it * 32;
    f32x4 v = NT ? __builtin_nontemporal_load(&tab4[(size_t)sidx[l] * 8 + c])
                 : tab4[(size_t)sidx[l] * 8 + c];
    acc += v;
  }
  {
    const int l = s + 352;
    f32x4 v = NT ? __builtin_nontemporal_load(&tab4[(size_t)sidx[l] * 8 + c])
                 : tab4[(size_t)sidx[l] * 8 + c];
    if (s < 23) acc += v;
  }
  return make_float4(acc.x, acc.y, acc.z, acc.w);
}

__global__ __launch_bounds__(256) void seq_pool_kernel(SeqArgs args, float* __restrict__ x0) {
  const int bid = blockIdx.x;
  const int f   = bid % 9;   // feature fastest among consecutive blocks
  const int b   = bid / 9;
  const int tid = threadIdx.x;

  __shared__ int sidx[NLP];
  const int*   idx = args.idx[f];
  const float* tab = args.tab[f];

  for (int i = tid; i < NLP; i += 256) sidx[i] = (i < NL) ? idx[b * NL + i] : idx[b * NL];
  __syncthreads();

  const int c = tid & 7;    // float4 column within the 32-float row
  const int s = tid >> 3;   // 0..31 slice over sequence positions

  float4 acc = (f == 1 || f == 2) ? gather_pool_body<true>(tab, sidx, s, c)
                                  : gather_pool_body<false>(tab, sidx, s, c);

  #pragma unroll
  for (int off = 8; off <= 32; off <<= 1) {
    acc.x += __shfl_xor(acc.x, off, 64);
    acc.y += __shfl_xor(acc.y, off, 64);
    acc.z += __shfl_xor(acc.z, off, 64);
    acc.w += __shfl_xor(acc.w, off, 64);
  }

  __shared__ float4 wpart[4][8];
  const int wave = tid >> 6;
  const int lane = tid & 63;
  if (lane < 8) wpart[wave][lane] = acc;
  __syncthreads();

  if (tid < 8) {
    float4 s0 = wpart[0][tid], s1 = wpart[1][tid], s2 = wpart[2][tid], s3 = wpart[3][tid];
    const float inv = 1.0f / (float)NL;
    float4 r;
    r.x = (s0.x + s1.x + s2.x + s3.x) * inv;
    r.y = (s0.y + s1.y + s2.y + s3.y) * inv;
    r.z = (s0.z + s1.z + s2.z + s3.z) * inv;
    r.w = (s0.w + s1.w + s2.w + s3.w) * inv;
    float* out = x0 + (size_t)b * DIN + (6 + f) * NEMB + tid * 4;
    *reinterpret_cast<float4*>(out) = r;
  }
}

// ---------------------------------------------------------------------------
// Kernel 2: fused scalar-gather + DCN cross layer. One wave per row.
// ---------------------------------------------------------------------------
struct ScalArgs {
  const int*   idx[6];
  const float* tab[6];
};

__global__ __launch_bounds__(64) void cross_scalar_kernel(ScalArgs args,
                                                          float* __restrict__ x0,
                                                          const float* __restrict__ V,
                                                          const float* __restrict__ U,
                                                          const float* __restrict__ bias) {
  const int b    = blockIdx.x;
  const int lane = threadIdx.x;
  float* row = x0 + (size_t)b * DIN;

  float xv[8];
  float t[5] = {0.f, 0.f, 0.f, 0.f, 0.f};
  #pragma unroll
  for (int i = 0; i < 8; ++i) {
    int j = lane + i * 64;
    float x;
    if (i < 3) {                       // scalar-feature region: j in [0,192)
      int f = j >> 5, d = j & 31;
      x = args.tab[f][(size_t)args.idx[f][b] * NEMB + d];
    } else if (j < DIN) {              // pooled seq region from x0
      x = row[j];
    } else {
      x = 0.f;
    }
    xv[i] = x;
    if (j < DIN) {
      #pragma unroll
      for (int p = 0; p < 5; ++p) t[p] += x * V[j * 5 + p];
    }
  }
  #pragma unroll
  for (int p = 0; p < 5; ++p) {
    float v = t[p];
    for (int off = 32; off; off >>= 1) v += __shfl_xor(v, off, 64);
    t[p] = v;
  }
  #pragma unroll
  for (int i = 0; i < 8; ++i) {
    int j = lane + i * 64;
    if (j < DIN) {
      float proj = bias[j];
      #pragma unroll
      for (int p = 0; p < 5; ++p) proj += t[p] * U[p * DIN + j];
      row[j] = xv[i] * proj + xv[i];
    }
  }
}

// ---------------------------------------------------------------------------
// Kernel 3: bf16-MFMA GEMM, C = relu?(A[M,K] @ W[K,N] + bias)
// Block 64x64, 4 waves (each a 32x32 quadrant = 2x2 16x16 frags), BK=32.
// ---------------------------------------------------------------------------
template <bool RELU>
__global__ __launch_bounds__(256) void gemm_mfma_kernel(const float* __restrict__ A,
                                                        const float* __restrict__ W,
                                                        const float* __restrict__ bias,
                                                        float* __restrict__ C,
                                                        int M, int N, int K) {
  const int tid  = threadIdx.x;
  const int m0   = blockIdx.y * 64;
  const int n0   = blockIdx.x * 64;
  const int wave = tid >> 6;
  const int lane = tid & 63;
  const int wm   = wave >> 1;
  const int wn   = wave & 1;

  __shared__ short As[64][40];   // [m][k], bf16 bits
  __shared__ short Bs[64][40];   // [n][k], bf16 bits (W transposed in LDS)

  f32x4 acc[2][2];
  #pragma unroll
  for (int i = 0; i < 2; ++i)
    #pragma unroll
    for (int j = 0; j < 2; ++j)
      acc[i][j] = (f32x4){0.f, 0.f, 0.f, 0.f};

  const int am  = tid >> 2;   // 0..63
  const int akq = tid & 3;    // k chunk of 8
  const int bn  = tid & 63;   // 0..63
  const int bkg = tid >> 6;   // k chunk of 8

  for (int k0 = 0; k0 < K; k0 += 32) {
    {
      const float* ap = A + (size_t)(m0 + am) * K + k0 + akq * 8;
      float4 a0 = *reinterpret_cast<const float4*>(ap);
      float4 a1 = *reinterpret_cast<const float4*>(ap + 4);
      short8 av = { f2bf(a0.x), f2bf(a0.y), f2bf(a0.z), f2bf(a0.w),
                    f2bf(a1.x), f2bf(a1.y), f2bf(a1.z), f2bf(a1.w) };
      *reinterpret_cast<short8*>(&As[am][akq * 8]) = av;
    }
    {
      float bv[8];
      #pragma unroll
      for (int i = 0; i < 8; ++i)
        bv[i] = W[(size_t)(k0 + bkg * 8 + i) * N + n0 + bn];
      short8 wv = { f2bf(bv[0]), f2bf(bv[1]), f2bf(bv[2]), f2bf(bv[3]),
                    f2bf(bv[4]), f2bf(bv[5]), f2bf(bv[6]), f2bf(bv[7]) };
      *reinterpret_cast<short8*>(&Bs[bn][bkg * 8]) = wv;
    }
    __syncthreads();

    short8 bf[2];
    #pragma unroll
    for (int fn = 0; fn < 2; ++fn)
      bf[fn] = *reinterpret_cast<const short8*>(&Bs[wn * 32 + fn * 16 + (lane & 15)][(lane >> 4) * 8]);
    #pragma unroll
    for (int fm = 0; fm < 2; ++fm) {
      short8 af = *reinterpret_cast<const short8*>(&As[wm * 32 + fm * 16 + (lane & 15)][(lane >> 4) * 8]);
      #pragma unroll
      for (int fn = 0; fn < 2; ++fn)
        acc[fm][fn] = __builtin_amdgcn_mfma_f32_16x16x32_bf16(af, bf[fn], acc[fm][fn], 0, 0, 0);
    }
    __syncthreads();
  }

  #pragma unroll
  for (int fm = 0; fm < 2; ++fm) {
    #pragma unroll
    for (int fn = 0; fn < 2; ++fn) {
      const int col  = n0 + wn * 32 + fn * 16 + (lane & 15);
      const float bc = bias[col];
      #pragma unroll
      for (int r = 0; r < 4; ++r) {
        const int m = m0 + wm * 32 + fm * 16 + (lane >> 4) * 4 + r;
        float x = acc[fm][fn][r] + bc;
        if (RELU) x = fmaxf(x, 0.f);
        C[(size_t)m * N + col] = x;
      }
    }
  }
}

// ---------------------------------------------------------------------------
// Kernel 4: layer-3 bf16-MFMA GEMM (N=128) + bias + row L2-normalize -> out
// ---------------------------------------------------------------------------
__global__ __launch_bounds__(256) void gemm3_norm_kernel(const float* __restrict__ A,
                                                         const float* __restrict__ W,
                                                         const float* __restrict__ bias,
                                                         float* __restrict__ out,
                                                         int M, int K) {
  const int N    = 128;
  const int tid  = threadIdx.x;
  const int m0   = blockIdx.x * 32;
  const int wave = tid >> 6;
  const int lane = tid & 63;

  __shared__ short As[32][40];    // [m][k]
  __shared__ short Bs[128][40];   // [n][k]

  f32x4 acc[2][2];
  #pragma unroll
  for (int i = 0; i < 2; ++i)
    #pragma unroll
    for (int j = 0; j < 2; ++j)
      acc[i][j] = (f32x4){0.f, 0.f, 0.f, 0.f};

  const int am  = tid >> 3;   // 0..31
  const int akq = tid & 7;    // k chunk of 4
  const int bn  = tid & 127;  // 0..127
  const int bkg = tid >> 7;   // k chunk of 16

  for (int k0 = 0; k0 < K; k0 += 32) {
    {
      float4 a0 = *reinterpret_cast<const float4*>(A + (size_t)(m0 + am) * K + k0 + akq * 4);
      short4v av = { f2bf(a0.x), f2bf(a0.y), f2bf(a0.z), f2bf(a0.w) };
      *reinterpret_cast<short4v*>(&As[am][akq * 4]) = av;
    }
    {
      float bv[16];
      #pragma unroll
      for (int i = 0; i < 16; ++i)
        bv[i] = W[(size_t)(k0 + bkg * 16 + i) * N + bn];
      short8 w0 = { f2bf(bv[0]),  f2bf(bv[1]),  f2bf(bv[2]),  f2bf(bv[3]),
                    f2bf(bv[4]),  f2bf(bv[5]),  f2bf(bv[6]),  f2bf(bv[7]) };
      short8 w1 = { f2bf(bv[8]),  f2bf(bv[9]),  f2bf(bv[10]), f2bf(bv[11]),
                    f2bf(bv[12]), f2bf(bv[13]), f2bf(bv[14]), f2bf(bv[15]) };
      *reinterpret_cast<short8*>(&Bs[bn][bkg * 16])     = w0;
      *reinterpret_cast<short8*>(&Bs[bn][bkg * 16 + 8]) = w1;
    }
    __syncthreads();

    short8 bf[2];
    #pragma unroll
    for (int fn = 0; fn < 2; ++fn)
      bf[fn] = *reinterpret_cast<const short8*>(&Bs[wave * 32 + fn * 16 + (lane & 15)][(lane >> 4) * 8]);
    #pragma unroll
    for (int fm = 0; fm < 2; ++fm) {
      short8 af = *reinterpret_cast<const short8*>(&As[fm * 16 + (lane & 15)][(lane >> 4) * 8]);
      #pragma unroll
      for (int fn = 0; fn < 2; ++fn)
        acc[fm][fn] = __builtin_amdgcn_mfma_f32_16x16x32_bf16(af, bf[fn], acc[fm][fn], 0, 0, 0);
    }
    __syncthreads();
  }

  float val[2][2][4];
  float psq[2][4] = {};
  #pragma unroll
  for (int fm = 0; fm < 2; ++fm)
    #pragma unroll
    for (int fn = 0; fn < 2; ++fn) {
      const int col  = wave * 32 + fn * 16 + (lane & 15);
      const float bc = bias[col];
      #pragma unroll
      for (int r = 0; r < 4; ++r) {
        float x = acc[fm][fn][r] + bc;
        val[fm][fn][r] = x;
        psq[fm][r] += x * x;
      }
    }

  #pragma unroll
  for (int off = 1; off < 16; off <<= 1)
    #pragma unroll
    for (int fm = 0; fm < 2; ++fm)
      #pragma unroll
      for (int r = 0; r < 4; ++r)
        psq[fm][r] += __shfl_xor(psq[fm][r], off, 64);

  __shared__ float part[4][32];
  if ((lane & 15) == 0) {
    #pragma unroll
    for (int fm = 0; fm < 2; ++fm)
      #pragma unroll
      for (int r = 0; r < 4; ++r)
        part[wave][fm * 16 + (lane >> 4) * 4 + r] = psq[fm][r];
  }
  __syncthreads();

  __shared__ float rn[32];
  if (tid < 32)
    rn[tid] = 1.0f / sqrtf(fmaxf(part[0][tid] + part[1][tid] + part[2][tid] + part[3][tid], 1e-12f));
  __syncthreads();

  #pragma unroll
  for (int fm = 0; fm < 2; ++fm)
    #pragma unroll
    for (int fn = 0; fn < 2; ++fn) {
      const int col = wave * 32 + fn * 16 + (lane & 15);
      #pragma unroll
      for (int r = 0; r < 4; ++r) {
        const int mrow = fm * 16 + (lane >> 4) * 4 + r;
        out[(size_t)(m0 + mrow) * N + col] = val[fm][fn][r] * rn[mrow];
      }
    }
}

// ---------------------------------------------------------------------------
// kernel_launch
// ---------------------------------------------------------------------------
extern "C" void kernel_launch(void* const* d_in, const int* in_sizes, int n_in,
                              void* d_out, int out_size, void* d_ws, size_t ws_size,
                              hipStream_t stream) {
  const int*   idx[15];
  const float* tab[15];
  for (int i = 0; i < 15; ++i) {
    idx[i] = (const int*)d_in[i];
    tab[i] = (const float*)d_in[15 + i];
  }
  const float* cross_V = (const float*)d_in[30];
  const float* cross_U = (const float*)d_in[31];
  const float* cross_b = (const float*)d_in[32];
  const float* W1 = (const float*)d_in[33];
  const float* b1 = (const float*)d_in[34];
  const float* W2 = (const float*)d_in[35];
  const float* b2 = (const float*)d_in[36];
  const float* W3 = (const float*)d_in[37];
  const float* b3 = (const float*)d_in[38];
  float* out = (float*)d_out;

  // workspace: x0 [B,480] | h1 [B,512] | h2 [B,256]  (~10.2 MB)
  float* x0 = (float*)d_ws;
  float* h1 = x0 + (size_t)NB * DIN;
  float* h2 = h1 + (size_t)NB * 512;

  SeqArgs sa;
  for (int i = 0; i < 9; ++i) { sa.idx[i] = idx[6 + i]; sa.tab[i] = tab[6 + i]; }
  ScalArgs ca;
  for (int i = 0; i < 6; ++i) { ca.idx[i] = idx[i]; ca.tab[i] = tab[i]; }

  hipLaunchKernelGGL(seq_pool_kernel, dim3(NB * 9), dim3(256), 0, stream, sa, x0);
  hipLaunchKernelGGL(cross_scalar_kernel, dim3(NB), dim3(64), 0, stream,
                     ca, x0, cross_V, cross_U, cross_b);
  hipLaunchKernelGGL((gemm_mfma_kernel<true>), dim3(512 / 64, NB / 64), dim3(256), 0, stream,
                     x0, W1, b1, h1, NB, 512, DIN);
  hipLaunchKernelGGL((gemm_mfma_kernel<true>), dim3(256 / 64, NB / 64), dim3(256), 0, stream,
                     h1, W2, b2, h2, NB, 256, 512);
  hipLaunchKernelGGL(gemm3_norm_kernel, dim3(NB / 32), dim3(256), 0, stream,
                     h2, W3, b3, out, NB, 256);
}